// Round 17
// baseline (152.886 us; speedup 1.0000x reference)
//
#include <hip/hip_runtime.h>
#include <hip/hip_bf16.h>
#include <math.h>

#define B_   8
#define T_   128
#define D_   512
#define M_   2048
#define HID_ 128
#define BT_  1024

typedef __attribute__((ext_vector_type(8))) short short8t;
typedef __attribute__((ext_vector_type(8))) unsigned short ushort8t;
typedef __attribute__((ext_vector_type(4))) unsigned short ushort4t;
typedef __attribute__((ext_vector_type(4))) float f32x4;
typedef __hip_bfloat16 bf16;

// ws layout (float offsets; all multiples of 16 -> 64B aligned)
#define OFF_SCAL   0L
#define OFF_QKV    16L                            // 1024*1536 f32
#define OFF_KP     (OFF_QKV + 1572864L)           // [KR|KI] bf16 exclusive prefix (2*BT*M bf16)
#define OFF_VRAW   (OFF_KP + 2097152L)
#define OFF_VF     (OFF_VRAW + 524288L)
#define OFF_HFEAT  (OFF_VF + 524288L)
// bf16 buffers (size in floats = elems/2)
#define OFF_EB     (OFF_HFEAT + 524288L)          // 1024x512
#define OFF_WQKVT  (OFF_EB + 262144L)             // 1536x512
#define OFF_VP1T   (OFF_WQKVT + 393216L)          // 512x512
#define OFF_VP2T   (OFF_VP1T + 131072L)
#define OFF_RO2T   (OFF_VP2T + 131072L)           // 512x128
#define OFF_QCAT   (OFF_RO2T + 32768L)            // 1024x4096
#define OFF_KCAT   (OFF_QCAT + 2097152L)          // 1024x4096
#define OFF_DKT    (OFF_KCAT + 2097152L)          // 2x8x2048x128
#define OFF_VTB    (OFF_DKT + 2097152L)           // 8x512x128
#define OFF_VLNB   (OFF_VTB + 262144L)            // 1024x512
#define OFF_V1B    (OFF_VLNB + 262144L)           // 1024x512
#define OFF_SCOA   (OFF_V1B + 262144L)            // 8x128x128 f32 split-K accumulator
#define OFF_QSUM   (OFF_SCOA + 131072L)           // 4x32768 f32 prefix quarter sums
#define OFF_PCAT   (OFF_QSUM + 131072L)           // 1024x4096 bf16 [ReP|ImP]
#define OFF_RO1F   (OFF_PCAT + 2097152L)          // 128x4096 bf16 [ReG|ImG]
#define OFF_HACC   (OFF_RO1F + 262144L)           // 1024x128 f32

#define FLAG_BIAS     1
#define FLAG_GELU     2
#define FLAG_ROWSCALE 4
#define FLAG_ATOMIC   8

__device__ __forceinline__ float gelu_f(float x) {
    return 0.5f * x * (1.0f + erff(x * 0.70710678118654752440f));
}

__device__ __forceinline__ float b2f(unsigned short u) {
    return __uint_as_float(((unsigned int)u) << 16);
}

#define PIDX(i) ((i) + ((i) >> 5))

template<int M>
__device__ __forceinline__ void dif_one(float* re, float* im, int tid) {
    #pragma unroll
    for (int u = 0; u < 4; ++u) {
        int q = u * 256 + tid;
        int k = q & (M - 1);
        int i = (q / M) * (2 * M) + k;
        float s, c;
        __sincosf((float)k * (3.14159265358979323846f / (float)M), &s, &c);
        int p0 = PIDX(i), p1 = PIDX(i + M);
        float ar = re[p0], ai = im[p0], br = re[p1], bi = im[p1];
        re[p0] = ar + br; im[p0] = ai + bi;
        float dr = ar - br, di = ai - bi;
        re[p1] = dr * c + di * s;
        im[p1] = di * c - dr * s;
    }
}

// ==== fused preprocessing: scal+zero | e-cast | 6x weight transpose | ro1 FFT ====
__global__ __launch_bounds__(256) void preproc_kernel(
    const float* tq, const float* tk, const float* om, const float* gf, const float* gv,
    float* scal, float* scoacc, float* hacc,
    const float4* __restrict__ e4, ushort4t* __restrict__ eb4,
    const float* w0, const float* w1, const float* w2, const float* w3,
    const float* w4, const float* w5,
    bf16* d0, bf16* d1, bf16* d2, bf16* d3, bf16* d4, bf16* d5,
    const float* __restrict__ ro_w1, bf16* __restrict__ ro1f)
{
    __shared__ float smem[4224];   // 16.9 KB union
    int blk = blockIdx.x, tid = threadIdx.x;

    if (blk < 1024) {
        int idx = blk * 256 + tid;
        if (idx < 131072) scoacc[idx] = 0.f;
        else hacc[idx - 131072] = 0.f;
        if (idx == 0) {
            scal[0] = 0.5f * tanhf(tq[0]);
            scal[1] = 0.5f * tanhf(tk[0]);
            scal[2] = 0.5f * tanhf(om[0]);
            scal[3] = 0.25f / (1.0f + expf(-gf[0]));
            scal[4] = 0.25f / (1.0f + expf(-gv[0]));
        }
        return;
    }
    if (blk < 1536) {
        int i = (blk - 1024) * 256 + tid;   // < 131072
        float4 v = e4[i];
        ushort4t o;
        bf16 h0 = __float2bfloat16(v.x), h1 = __float2bfloat16(v.y);
        bf16 h2 = __float2bfloat16(v.z), h3 = __float2bfloat16(v.w);
        o[0] = *(unsigned short*)&h0; o[1] = *(unsigned short*)&h1;
        o[2] = *(unsigned short*)&h2; o[3] = *(unsigned short*)&h3;
        eb4[i] = o;
        return;
    }
    if (blk < 3072) {
        int zz = blk - 1536;
        int wz = zz >> 8;
        int rem = zz & 255;
        int by = rem >> 4, bx = rem & 15;
        const float* src; bf16* dst; int R = 512;
        if (wz == 0)      { src = w0; dst = d0; }
        else if (wz == 1) { src = w1; dst = d1; }
        else if (wz == 2) { src = w2; dst = d2; }
        else if (wz == 3) { src = w3; dst = d3; }
        else if (wz == 4) { src = w4; dst = d4; }
        else              { src = w5; dst = d5; R = 128; }
        int c0 = bx * 32, r0 = by * 32;
        if (r0 >= R) return;
        float (*tile)[33] = (float(*)[33])smem;
        int tx = tid & 31, ty = tid >> 5;
        for (int rr = ty; rr < 32; rr += 8) {
            int r = r0 + rr;
            tile[rr][tx] = (r < R) ? src[(long)r * 512 + c0 + tx] : 0.f;
        }
        __syncthreads();
        int r = r0 + tx;
        if (r < R)
            for (int cc = ty; cc < 32; cc += 8)
                dst[(long)(c0 + cc) * R + r] = __float2bfloat16(tile[tx][cc]);
        return;
    }
    {   // ro1fft
        int j = blk - 3072;
        float* Rs = smem;
        float* Is = smem + 2112;
        for (int u = 0; u < 8; ++u) {
            int n = u * 256 + tid;
            Rs[PIDX(n)] = ro_w1[(long)n * HID_ + j];
            Is[PIDX(n)] = 0.f;
        }
        __syncthreads();
#define FSTEP(MM) dif_one<MM>(Rs, Is, tid); __syncthreads();
        FSTEP(1024) FSTEP(512) FSTEP(256) FSTEP(128) FSTEP(64)
        FSTEP(32) FSTEP(16) FSTEP(8) FSTEP(4) FSTEP(2) FSTEP(1)
#undef FSTEP
        unsigned short* op = (unsigned short*)(ro1f + (long)j * 4096);
        for (int u = 0; u < 8; ++u) {
            int r = u * 256 + tid;
            int pr = PIDX(r);
            bf16 re = __float2bfloat16(Rs[pr]);
            bf16 im = __float2bfloat16(Is[pr]);
            op[r]        = *(unsigned short*)&re;
            op[2048 + r] = *(unsigned short*)&im;
        }
    }
}

// ==== fused sketch + vTb transpose ====
__global__ __launch_bounds__(256) void sketchvtb_kernel(const float* __restrict__ qkv,
                                                        const float* __restrict__ sign,
                                                        const float* __restrict__ scal,
                                                        const int* __restrict__ h,
                                                        bf16* __restrict__ qcat,
                                                        bf16* __restrict__ kcat,
                                                        bf16* __restrict__ vTb) {
    __shared__ float smem[4 * M_];
    int blk = blockIdx.x, tid = threadIdx.x;
    if (blk < 1024) {
        int bt = blk;
        float* s0 = smem;
        float* s1 = smem + M_;
        float* s2 = smem + 2 * M_;
        float* s3 = smem + 3 * M_;
        for (int j = tid; j < M_; j += 256) { s0[j] = 0.f; s1[j] = 0.f; s2[j] = 0.f; s3[j] = 0.f; }
        __syncthreads();
        int t = bt & 127;
        float thq = scal[0], thk = scal[1], omg = scal[2];
        float ft = (float)t;
        for (int i = tid; i < D_; i += 256) {
            float q = qkv[(long)bt * 1536 + i];
            float k = qkv[(long)bt * 1536 + 512 + i];
            float sg = sign[i];
            float sq_, cq_, sk_, ck_;
            __sincosf(thq * q - omg * ft, &sq_, &cq_);
            __sincosf(thk * k + omg * ft, &sk_, &ck_);
            int m = h[i];
            atomicAdd(&s0[m], q * cq_ * sg);
            atomicAdd(&s1[m], q * sq_ * sg);
            atomicAdd(&s2[m], k * ck_ * sg);
            atomicAdd(&s3[m], k * sk_ * sg);
        }
        __syncthreads();
        long qb = (long)bt * 4096;
        for (int j = tid; j < M_; j += 256) {
            qcat[qb + j]        = __float2bfloat16(s0[j]);
            qcat[qb + 2048 + j] = __float2bfloat16(s1[j]);
            kcat[qb + j]        = __float2bfloat16(s2[j]);
            kcat[qb + 2048 + j] = __float2bfloat16(-s3[j]);
        }
        return;
    }
    {   // vTb transpose
        int zz = blk - 1024;
        int b = zz >> 6;
        int rem = zz & 63;
        int by = rem >> 4, bx = rem & 15;
        int c0 = bx * 32, r0 = by * 32;
        float (*tile)[33] = (float(*)[33])smem;
        int tx = tid & 31, ty = tid >> 5;
        const float* in = qkv + 1024 + (long)b * 196608L;
        for (int rr = ty; rr < 32; rr += 8)
            tile[rr][tx] = in[(long)(r0 + rr) * 1536 + c0 + tx];
        __syncthreads();
        bf16* out = vTb + (long)b * 65536L;
        for (int cc = ty; cc < 32; cc += 8)
            out[(long)(c0 + cc) * 128 + r0 + tx] = __float2bfloat16(tile[tx][cc]);
    }
}

// ---- two-phase exclusive prefix over t, reading bf16 kcat ----
__global__ __launch_bounds__(256) void prefix_p1(const bf16* __restrict__ kcat,
                                                 float* __restrict__ qsum) {
    int idx = blockIdx.x * 256 + threadIdx.x;   // 131072
    int col = idx & 32767, q = idx >> 15;
    int m = col & 2047, b = (col >> 11) & 7, comp = col >> 14;
    const unsigned short* src = (const unsigned short*)kcat
        + ((long)(b * 128 + q * 32) * 4096L + (long)comp * 2048L + m);
    float s = 0.f;
    #pragma unroll 8
    for (int i = 0; i < 32; ++i) s += b2f(src[(long)i * 4096L]);
    if (comp) s = -s;
    qsum[(long)q * 32768 + col] = s;
}

__global__ __launch_bounds__(256) void prefix_p2(const bf16* __restrict__ kcat,
                                                 const float* __restrict__ qsum,
                                                 bf16* __restrict__ KP16,
                                                 bf16* __restrict__ dkT,
                                                 float* __restrict__ kf_out) {
    int idx = blockIdx.x * 256 + threadIdx.x;   // 131072
    int col = idx & 32767, q = idx >> 15;
    int m = col & 2047, b = (col >> 11) & 7, comp = col >> 14;
    const unsigned short* src = (const unsigned short*)kcat
        + ((long)(b * 128 + q * 32) * 4096L + (long)comp * 2048L + m);
    bf16* dst = KP16 + (long)comp * BT_ * M_ + (long)b * T_ * M_ + m + (long)(q * 32) * M_;
    bf16* dkt = dkT + (long)comp * 2097152L + (long)b * 262144L + (long)m * 128L + (long)(q * 32);
    float acc = 0.f;
    for (int p = 0; p < q; ++p) acc += qsum[(long)p * 32768 + col];
    float sgn = comp ? -1.f : 1.f;
    #pragma unroll 4
    for (int i = 0; i < 32; ++i) {
        float v = sgn * b2f(src[(long)i * 4096L]);
        dst[(long)i * M_] = __float2bfloat16(acc);
        dkt[i] = __float2bfloat16(v);
        acc += v;
    }
    if (q == 3) kf_out[((long)b * 2 + comp) * M_ + m] = acc;
}

// fused 3-stage radix-8 DIF pass on both (K,Q) arrays.
template<int S>
__device__ __forceinline__ void dif8_pair(float* r0, float* i0a, float* r1, float* i1a, int tid) {
    int k = tid % S;
    int grp = tid / S;
    int base = grp * 8 * S + k;
    float sw, cw;
    __sincosf((float)k * (3.14159265358979323846f / (4.0f * (float)S)), &sw, &cw);
    float wr = cw, wi = -sw;
    float w2r = wr * wr - wi * wi, w2i = 2.f * wr * wi;
    float w4r = w2r * w2r - w2i * w2i, w4i = 2.f * w2r * w2i;
    const float RH = 0.70710678118654752440f;
    float t1r[4] = {wr, (wr + wi) * RH, wi, (wi - wr) * RH};
    float t1i[4] = {wi, (wi - wr) * RH, -wr, -(wr + wi) * RH};
    float u0r = w2r, u0i = w2i;
    float u1r = w2i, u1i = -w2r;
    #pragma unroll
    for (int a = 0; a < 2; ++a) {
        float* re = a ? r1 : r0;
        float* im = a ? i1a : i0a;
        float xr[8], xi[8];
        #pragma unroll
        for (int r = 0; r < 8; ++r) { int p = PIDX(base + r * S); xr[r] = re[p]; xi[r] = im[p]; }
        #pragma unroll
        for (int r = 0; r < 4; ++r) {
            float ar = xr[r], ai = xi[r], br = xr[r + 4], bi = xi[r + 4];
            xr[r] = ar + br; xi[r] = ai + bi;
            float dr = ar - br, di = ai - bi;
            xr[r + 4] = dr * t1r[r] - di * t1i[r];
            xi[r + 4] = dr * t1i[r] + di * t1r[r];
        }
        #pragma unroll
        for (int hb = 0; hb < 8; hb += 4) {
            #pragma unroll
            for (int r = 0; r < 2; ++r) {
                float tr = (r == 0) ? u0r : u1r, ti = (r == 0) ? u0i : u1i;
                float ar = xr[hb + r], ai = xi[hb + r], br = xr[hb + r + 2], bi = xi[hb + r + 2];
                xr[hb + r] = ar + br; xi[hb + r] = ai + bi;
                float dr = ar - br, di = ai - bi;
                xr[hb + r + 2] = dr * tr - di * ti;
                xi[hb + r + 2] = dr * ti + di * tr;
            }
        }
        #pragma unroll
        for (int r = 0; r < 8; r += 2) {
            float ar = xr[r], ai = xi[r], br = xr[r + 1], bi = xi[r + 1];
            xr[r] = ar + br; xi[r] = ai + bi;
            float dr = ar - br, di = ai - bi;
            xr[r + 1] = dr * w4r - di * w4i;
            xi[r + 1] = dr * w4i + di * w4r;
        }
        #pragma unroll
        for (int r = 0; r < 8; ++r) { int p = PIDX(base + r * S); re[p] = xr[r]; im[p] = xi[r]; }
    }
}

// GEMM inner body macro shared by fused launch kernels (bf16 TN, 64x64 tile)
#define GEMM_CORE(ABASE, BBASE, KK)                                            \
    for (int kt = k0; kt < k0 + klen; kt += 32) {                              \
        *(float4*)&As[lrow][lk] = *(const float4*)&(ABASE)[(long)lrow * (KK) + kt + lk]; \
        *(float4*)&Bs[lrow][lk] = *(const float4*)&(BBASE)[(long)lrow * (KK) + kt + lk]; \
        __syncthreads();                                                       \
        short8t a0 = *(const short8t*)&As[wr + fm][fk];                        \
        short8t a1 = *(const short8t*)&As[wr + 16 + fm][fk];                   \
        short8t b0 = *(const short8t*)&Bs[wc + fm][fk];                        \
        short8t b1 = *(const short8t*)&Bs[wc + 16 + fm][fk];                   \
        acc00 = __builtin_amdgcn_mfma_f32_16x16x32_bf16(a0, b0, acc00, 0, 0, 0); \
        acc01 = __builtin_amdgcn_mfma_f32_16x16x32_bf16(a0, b1, acc01, 0, 0, 0); \
        acc10 = __builtin_amdgcn_mfma_f32_16x16x32_bf16(a1, b0, acc10, 0, 0, 0); \
        acc11 = __builtin_amdgcn_mfma_f32_16x16x32_bf16(a1, b1, acc11, 0, 0, 0); \
        __syncthreads();                                                       \
    }

// ==== fused: fwdfft [0,1024) | scores GEMM [1024,1408) | Hf GEMM [1408,5504) ====
__global__ __launch_bounds__(256) void fftscohf_kernel(const bf16* __restrict__ qcat,
                                                       const bf16* __restrict__ KP16,
                                                       bf16* __restrict__ pcat,
                                                       const bf16* __restrict__ kcat,
                                                       float* __restrict__ scoacc,
                                                       const bf16* __restrict__ vTb,
                                                       const bf16* __restrict__ dkT,
                                                       float* __restrict__ hf) {
    __shared__ float smem[8448];   // 33 KB union
    int blk = blockIdx.x, tid = threadIdx.x;

    if (blk >= 1408) {   // ---- Hf GEMM: vTb(512x128) @ dkT^T(2048x128), per (b,c) ----
        int zz = blk - 1408;            // [0,4096): flatten (32,8,16)
        int tbx = zz & 31, tby = (zz >> 5) & 7, bz = zz >> 8;
        int b = bz & 7, c = bz >> 3;
        const int K = 128;
        int klen = 128, k0 = 0;
        bf16 (*As)[44] = (bf16(*)[44])smem;
        bf16 (*Bs)[44] = (bf16(*)[44])(smem + 1408);
        const bf16* Ab = vTb + (long)b * 65536L + (long)tby * 64 * K;
        const bf16* Bb = dkT + (long)c * 2097152L + (long)b * 262144L + (long)tbx * 64 * K;
        int lrow = tid >> 2, lk = (tid & 3) * 8;
        int w = tid >> 6, lane = tid & 63;
        int wr = (w >> 1) * 32, wc = (w & 1) * 32;
        int fm = lane & 15, fk = (lane >> 4) * 8;
        f32x4 acc00 = {0.f,0.f,0.f,0.f}, acc01 = acc00, acc10 = acc00, acc11 = acc00;
        GEMM_CORE(Ab, Bb, K)
        float* Cf = hf + (long)b * 2097152L + (long)c * 1048576L;
        int row_base = tby * 64 + wr + (lane >> 4) * 4;
        int col_base = tbx * 64 + wc + fm;
        #pragma unroll
        for (int fr = 0; fr < 2; ++fr)
            #pragma unroll
            for (int fc = 0; fc < 2; ++fc) {
                const f32x4& a = fr == 0 ? (fc == 0 ? acc00 : acc01) : (fc == 0 ? acc10 : acc11);
                #pragma unroll
                for (int r = 0; r < 4; ++r)
                    Cf[(long)(row_base + fr * 16 + r) * 2048 + col_base + fc * 16] = a[r];
            }
        return;
    }

    if (blk >= 1024) {   // ---- scores GEMM tile: flattened (3,1,128) TRI split-K ----
        int s = blk - 1024;            // [0,384)
        int xx = s % 3, bz = s / 3;    // bz in [0,128)
        int tby = (xx > 0) ? 1 : 0, tbx = (xx == 2) ? 1 : 0;
        int batch = bz >> 4, kslice = bz & 15;
        const int K = 4096;
        int klen = 256, k0 = kslice * 256;
        bf16 (*As)[44] = (bf16(*)[44])smem;
        bf16 (*Bs)[44] = (bf16(*)[44])(smem + 1408);
        const bf16* Ab = qcat + (long)batch * 524288L + (long)tby * 64 * K;
        const bf16* Bb = kcat + (long)batch * 524288L + (long)tbx * 64 * K;
        int lrow = tid >> 2, lk = (tid & 3) * 8;
        int w = tid >> 6, lane = tid & 63;
        int wr = (w >> 1) * 32, wc = (w & 1) * 32;
        int fm = lane & 15, fk = (lane >> 4) * 8;
        f32x4 acc00 = {0.f,0.f,0.f,0.f}, acc01 = acc00, acc10 = acc00, acc11 = acc00;
        GEMM_CORE(Ab, Bb, K)
        float* Cf = scoacc + (long)batch * 16384L;
        int row_base = tby * 64 + wr + (lane >> 4) * 4;
        int col_base = tbx * 64 + wc + fm;
        #pragma unroll
        for (int fr = 0; fr < 2; ++fr)
            #pragma unroll
            for (int fc = 0; fc < 2; ++fc) {
                const f32x4& a = fr == 0 ? (fc == 0 ? acc00 : acc01) : (fc == 0 ? acc10 : acc11);
                #pragma unroll
                for (int r = 0; r < 4; ++r)
                    atomicAdd(&Cf[(long)(row_base + fr * 16 + r) * 128 + col_base + fc * 16], a[r]);
            }
        return;
    }

    // ---- fwdfft per (b,t) ----
    float* KRs = smem;
    float* KIs = smem + 2112;
    float* QRs = smem + 4224;
    float* QIs = smem + 6336;
    int bt = blk;
    const unsigned short* qp = (const unsigned short*)(qcat + (long)bt * 4096);
    const unsigned short* kpr = (const unsigned short*)(KP16 + (long)bt * M_);
    const unsigned short* kpi = (const unsigned short*)(KP16 + (long)BT_ * M_ + (long)bt * M_);
    for (int u = 0; u < 8; ++u) {
        int j = u * 256 + tid;
        int pj = PIDX(j);
        KRs[pj] = b2f(kpr[j]);
        KIs[pj] = b2f(kpi[j]);
        QRs[pj] = b2f(qp[j]);
        QIs[pj] = b2f(qp[2048 + j]);
    }
    __syncthreads();
    dif8_pair<256>(KRs, KIs, QRs, QIs, tid);  __syncthreads();
    dif8_pair<32>(KRs, KIs, QRs, QIs, tid);   __syncthreads();

    float kr_[8], ki_[8], qr_[8], qi_[8];
    #pragma unroll
    for (int l = 0; l < 8; ++l) {
        int pj = PIDX(8 * tid + l);
        kr_[l] = KRs[pj]; ki_[l] = KIs[pj];
        qr_[l] = QRs[pj]; qi_[l] = QIs[pj];
    }

    const float C16[16] = {1.f, 0.98078528f, 0.92387953f, 0.83146961f,
                           0.70710678f, 0.55557023f, 0.38268343f, 0.19509032f,
                           0.f, -0.19509032f, -0.38268343f, -0.55557023f,
                           -0.70710678f, -0.83146961f, -0.92387953f, -0.98078528f};
    const float S16[16] = {0.f, 0.19509032f, 0.38268343f, 0.55557023f,
                           0.70710678f, 0.83146961f, 0.92387953f, 0.98078528f,
                           1.f, 0.98078528f, 0.92387953f, 0.83146961f,
                           0.70710678f, 0.55557023f, 0.38268343f, 0.19509032f};
    bool odd = (tid & 1) != 0;
    {
        bool hi2 = (tid & 2) != 0;
        #pragma unroll
        for (int l = 0; l < 8; ++l) {
            float c = odd ? C16[l + 8] : C16[l];
            float s = odd ? S16[l + 8] : S16[l];
            float pr, pi2, sr, si, dr, di;
            pr = __shfl_xor(kr_[l], 2); pi2 = __shfl_xor(ki_[l], 2);
            sr = kr_[l] + pr; si = ki_[l] + pi2;
            dr = pr - kr_[l]; di = pi2 - ki_[l];
            kr_[l] = hi2 ? (dr * c + di * s) : sr;
            ki_[l] = hi2 ? (di * c - dr * s) : si;
            pr = __shfl_xor(qr_[l], 2); pi2 = __shfl_xor(qi_[l], 2);
            sr = qr_[l] + pr; si = qi_[l] + pi2;
            dr = pr - qr_[l]; di = pi2 - qi_[l];
            qr_[l] = hi2 ? (dr * c + di * s) : sr;
            qi_[l] = hi2 ? (di * c - dr * s) : si;
        }
    }
    {
        #pragma unroll
        for (int l = 0; l < 8; ++l) {
            float c = C16[2 * l];
            float s = S16[2 * l];
            float pr, pi2, sr, si, dr, di;
            pr = __shfl_xor(kr_[l], 1); pi2 = __shfl_xor(ki_[l], 1);
            sr = kr_[l] + pr; si = ki_[l] + pi2;
            dr = pr - kr_[l]; di = pi2 - ki_[l];
            kr_[l] = odd ? (dr * c + di * s) : sr;
            ki_[l] = odd ? (di * c - dr * s) : si;
            pr = __shfl_xor(qr_[l], 1); pi2 = __shfl_xor(qi_[l], 1);
            sr = qr_[l] + pr; si = qi_[l] + pi2;
            dr = pr - qr_[l]; di = pi2 - qi_[l];
            qr_[l] = odd ? (dr * c + di * s) : sr;
            qi_[l] = odd ? (di * c - dr * s) : si;
        }
    }
    {
        const float C4[4] = {1.f, 0.70710678f, 0.f, -0.70710678f};
        const float S4[4] = {0.f, 0.70710678f, 1.f, 0.70710678f};
        #pragma unroll
        for (int l = 0; l < 4; ++l) {
            float ar, ai, br, bi, dr, di;
            ar = kr_[l]; ai = ki_[l]; br = kr_[l + 4]; bi = ki_[l + 4];
            kr_[l] = ar + br; ki_[l] = ai + bi;
            dr = ar - br; di = ai - bi;
            kr_[l + 4] = dr * C4[l] + di * S4[l];
            ki_[l + 4] = di * C4[l] - dr * S4[l];
            ar = qr_[l]; ai = qi_[l]; br = qr_[l + 4]; bi = qi_[l + 4];
            qr_[l] = ar + br; qi_[l] = ai + bi;
            dr = ar - br; di = ai - bi;
            qr_[l + 4] = dr * C4[l] + di * S4[l];
            qi_[l + 4] = di * C4[l] - dr * S4[l];
        }
    }
    #pragma unroll
    for (int b2 = 0; b2 < 8; b2 += 4) {
        {
            float ar = kr_[b2], ai = ki_[b2], br = kr_[b2 + 2], bi = ki_[b2 + 2];
            kr_[b2] = ar + br; ki_[b2] = ai + bi;
            kr_[b2 + 2] = ar - br; ki_[b2 + 2] = ai - bi;
            ar = qr_[b2]; ai = qi_[b2]; br = qr_[b2 + 2]; bi = qi_[b2 + 2];
            qr_[b2] = ar + br; qi_[b2] = ai + bi;
            qr_[b2 + 2] = ar - br; qi_[b2 + 2] = ai - bi;
        }
        {
            float ar = kr_[b2 + 1], ai = ki_[b2 + 1], br = kr_[b2 + 3], bi = ki_[b2 + 3];
            kr_[b2 + 1] = ar + br; ki_[b2 + 1] = ai + bi;
            float dr = ar - br, di = ai - bi;
            kr_[b2 + 3] = di; ki_[b2 + 3] = -dr;
            ar = qr_[b2 + 1]; ai = qi_[b2 + 1]; br = qr_[b2 + 3]; bi = qi_[b2 + 3];
            qr_[b2 + 1] = ar + br; qi_[b2 + 1] = ai + bi;
            dr = ar - br; di = ai - bi;
            qr_[b2 + 3] = di; qi_[b2 + 3] = -dr;
        }
    }
    #pragma unroll
    for (int i0 = 0; i0 < 8; i0 += 2) {
        float ar = kr_[i0], ai = ki_[i0], br = kr_[i0 + 1], bi = ki_[i0 + 1];
        kr_[i0] = ar + br; ki_[i0] = ai + bi;
        kr_[i0 + 1] = ar - br; ki_[i0 + 1] = ai - bi;
        ar = qr_[i0]; ai = qi_[i0]; br = qr_[i0 + 1]; bi = qi_[i0 + 1];
        qr_[i0] = ar + br; qi_[i0] = ai + bi;
        qr_[i0 + 1] = ar - br; qi_[i0 + 1] = ai - bi;
    }

    unsigned short* op = (unsigned short*)(pcat + (long)bt * 4096 + 8 * tid);
    ushort8t ore, oim;
    #pragma unroll
    for (int l = 0; l < 8; ++l) {
        float pr = qr_[l] * kr_[l] - qi_[l] * ki_[l];
        float pi2 = qr_[l] * ki_[l] + qi_[l] * kr_[l];
        bf16 hr = __float2bfloat16(pr);
        bf16 hi = __float2bfloat16(pi2);
        ore[l] = *(unsigned short*)&hr;
        oim[l] = *(unsigned short*)&hi;
    }
    *(ushort8t*)op = ore;
    *(ushort8t*)(op + 2048) = oim;
}

// ==== fused: v1b GEMM (blocks [0,128)) | hid split-K GEMM (blocks [128,384)) ====
__global__ __launch_bounds__(256) void v1hid_kernel(const bf16* __restrict__ vlnb,
                                                    const bf16* __restrict__ vp1T,
                                                    const float* __restrict__ vp_b1,
                                                    bf16* __restrict__ v1b,
                                                    const bf16* __restrict__ pcat,
                                                    const bf16* __restrict__ ro1f,
                                                    float* __restrict__ hacc) {
    __shared__ __align__(16) bf16 As[64][44];
    __shared__ __align__(16) bf16 Bs[64][44];
    int blk = blockIdx.x, tid = threadIdx.x;
    int lrow = tid >> 2, lk = (tid & 3) * 8;
    int w = tid >> 6, lane = tid & 63;
    int wr = (w >> 1) * 32, wc = (w & 1) * 32;
    int fm = lane & 15, fk = (lane >> 4) * 8;
    f32x4 acc00 = {0.f,0.f,0.f,0.f}, acc01 = acc00, acc10 = acc00, acc11 = acc00;

    if (blk < 128) {   // v1b = gelu(vlnb @ vp1T^T + vp_b1), K=512
        int tbx = blk & 7, tby = blk >> 3;
        const int K = 512;
        int klen = K, k0 = 0;
        const bf16* Ab = vlnb + (long)tby * 64 * K;
        const bf16* Bb = vp1T + (long)tbx * 64 * K;
        GEMM_CORE(Ab, Bb, K)
        int row_base = tby * 64 + wr + (lane >> 4) * 4;
        int col_base = tbx * 64 + wc + fm;
        #pragma unroll
        for (int fr = 0; fr < 2; ++fr)
            #pragma unroll
            for (int fc = 0; fc < 2; ++fc) {
                const f32x4& a = fr == 0 ? (fc == 0 ? acc00 : acc01) : (fc == 0 ? acc10 : acc11);
                #pragma unroll
                for (int r = 0; r < 4; ++r) {
                    int gi = row_base + fr * 16 + r, gj = col_base + fc * 16;
                    v1b[(long)gi * 512 + gj] = __float2bfloat16(gelu_f(a[r] + vp_b1[gj]));
                }
            }
        return;
    }
    {   // hid_pre split-K: pcat(1024x4096) @ ro1f^T(128x4096), atomic into hacc
        int s2 = blk - 128;            // [0,256): (2,16,8) flatten
        int tbx = s2 & 1, tby = (s2 >> 1) & 15, kslice = s2 >> 5;
        const int K = 4096;
        int klen = 512, k0 = kslice * 512;
        const bf16* Ab = pcat + (long)tby * 64 * K;
        const bf16* Bb = ro1f + (long)tbx * 64 * K;
        GEMM_CORE(Ab, Bb, K)
        int row_base = tby * 64 + wr + (lane >> 4) * 4;
        int col_base = tbx * 64 + wc + fm;
        #pragma unroll
        for (int fr = 0; fr < 2; ++fr)
            #pragma unroll
            for (int fc = 0; fc < 2; ++fc) {
                const f32x4& a = fr == 0 ? (fc == 0 ? acc00 : acc01) : (fc == 0 ? acc10 : acc11);
                #pragma unroll
                for (int r = 0; r < 4; ++r)
                    atomicAdd(&hacc[(long)(row_base + fr * 16 + r) * 128 + col_base + fc * 16], a[r]);
            }
    }
}

// MFMA bf16 TN GEMM (generic; used for qkv, vraw)
template<int FLAGS, int OUTB16, int AMODE>
__global__ __launch_bounds__(256) void gemm_mfma(
    const void* __restrict__ Av, const bf16* __restrict__ Bt,
    const float* __restrict__ bias, const float* __restrict__ abias,
    void* __restrict__ Cv,
    int K, int ldc, long abz, long bbz, long cbz, int splitk)
{
    __shared__ __align__(16) bf16 As[64][44];
    __shared__ __align__(16) bf16 Bs[64][44];
    int bz = blockIdx.z;
    int batch = bz, kslice = 0;
    if (FLAGS & FLAG_ATOMIC) { batch = bz / splitk; kslice = bz % splitk; }
    int tbx = blockIdx.x, tby = blockIdx.y;
    long aoff = (long)batch * abz + (long)tby * 64 * K;
    const bf16* Bb = Bt + (long)batch * bbz + (long)tbx * 64 * K;
    long coff = (long)batch * cbz;
    int tid = threadIdx.x;
    int lrow = tid >> 2;
    int lk = (tid & 3) * 8;
    int w = tid >> 6, lane = tid & 63;
    int wr = (w >> 1) * 32, wc = (w & 1) * 32;
    int fm = lane & 15, fk = (lane >> 4) * 8;
    f32x4 acc00 = {0.f,0.f,0.f,0.f}, acc01 = acc00, acc10 = acc00, acc11 = acc00;

    int klen = K / splitk;
    int k0 = kslice * klen;
    for (int kt = k0; kt < k0 + klen; kt += 32) {
        if (AMODE == 0) {
            const bf16* Ab = (const bf16*)Av + aoff;
            *(float4*)&As[lrow][lk] = *(const float4*)&Ab[(long)lrow * K + kt + lk];
        } else {
            const float* Af = (const float*)Av + aoff;
            int gk0 = kt + lk;
            float4 v0 = *(const float4*)&Af[(long)lrow * K + gk0];
            float4 v1 = *(const float4*)&Af[(long)lrow * K + gk0 + 4];
            float vv[8] = {v0.x, v0.y, v0.z, v0.w, v1.x, v1.y, v1.z, v1.w};
            int grow = tby * 64 + lrow;
            #pragma unroll
            for (int j = 0; j < 8; ++j) {
                float val = vv[j];
                int gk = gk0 + j;
                if (AMODE == 1) val = (gk < grow) ? val : 0.f;
                As[lrow][lk + j] = __float2bfloat16(val);
            }
        }
        *(float4*)&Bs[lrow][lk] = *(const float4*)&Bb[(long)lrow * K + kt + lk];
        __syncthreads();
        short8t a0 = *(const short8t*)&As[wr + fm][fk];
        short8t a1 = *(const short8t*)&As[wr + 16 + fm][fk];
        short8t b0 = *(const short8t*)&Bs[wc + fm][fk];
        short8t b1 = *(const short8t*)&Bs[wc + 16 + fm][fk];
        acc00 = __builtin_amdgcn_mfma_f32_16x16x32_bf16(a0, b0, acc00, 0, 0, 0);
        acc01 = __builtin_amdgcn_mfma_f32_16x16x32_bf16(a0, b1, acc01, 0, 0, 0);
        acc10 = __builtin_amdgcn_mfma_f32_16x16x32_bf16(a1, b0, acc10, 0, 0, 0);
        acc11 = __builtin_amdgcn_mfma_f32_16x16x32_bf16(a1, b1, acc11, 0, 0, 0);
        __syncthreads();
    }

    float* Cf = (float*)Cv;
    bf16* Cb = (bf16*)Cv;
    int row_base = tby * 64 + wr + (lane >> 4) * 4;
    int col_base = tbx * 64 + wc + fm;
    #pragma unroll
    for (int fr = 0; fr < 2; ++fr) {
        #pragma unroll
        for (int fc = 0; fc < 2; ++fc) {
            const f32x4& a = fr == 0 ? (fc == 0 ? acc00 : acc01) : (fc == 0 ? acc10 : acc11);
            #pragma unroll
            for (int r = 0; r < 4; ++r) {
                int gi = row_base + fr * 16 + r;
                int gj = col_base + fc * 16;
                float v = a[r];
                long ci = coff + (long)gi * ldc + gj;
                if (FLAGS & FLAG_ATOMIC) {
                    atomicAdd(&Cf[ci], v);
                } else {
                    if (FLAGS & FLAG_BIAS) v += bias[gj];
                    if (FLAGS & FLAG_GELU) v = gelu_f(v);
                    if (FLAGS & FLAG_ROWSCALE) v *= rsqrtf((float)(gi & 127) + 1.0f);
                    if (OUTB16) Cb[ci] = __float2bfloat16(v);
                    else        Cf[ci] = v;
                }
            }
        }
    }
}

// fused dual GEMM: z=0: vf = v1b @ vp2T^T + vp_b2;  z=1: hfeat = gelu(hacc..) @ ro2T^T + ro_b2
__global__ __launch_bounds__(256) void gemm_dual(
    const bf16* __restrict__ v1b, const bf16* __restrict__ vp2T, const float* __restrict__ vp_b2,
    const float* __restrict__ hacc, const bf16* __restrict__ ro2T, const float* __restrict__ ro_b1,
    const float* __restrict__ ro_b2, float* __restrict__ vf, float* __restrict__ hfeat)
{
    __shared__ __align__(16) bf16 As[64][44];
    __shared__ __align__(16) bf16 Bs[64][44];
    int tid = threadIdx.x;
    int lrow = tid >> 2, lk = (tid & 3) * 8;
    int w = tid >> 6, lane = tid & 63;
    int wr = (w >> 1) * 32, wc = (w & 1) * 32;
    int fm = lane & 15, fk = (lane >> 4) * 8;
    f32x4 acc00 = {0.f,0.f,0.f,0.f}, acc01 = acc00, acc10 = acc00, acc11 = acc00;
    int mode = blockIdx.z;
    int K = mode ? 128 : 512;
    const bf16* Bb = (mode ? ro2T : vp2T) + (long)blockIdx.x * 64 * K;

    for (int kt = 0; kt < K; kt += 32) {
        if (mode == 0) {
            const bf16* Ab = v1b + (long)blockIdx.y * 64 * K;
            *(float4*)&As[lrow][lk] = *(const float4*)&Ab[(long)lrow * K + kt + lk];
        } else {
            const float* Af = hacc + (long)blockIdx.y * 64 * K;
            int gk0 = kt + lk;
            float4 v0 = *(const float4*)&Af[(long)lrow * K + gk0];
            float4 v1 = *(const float4*)&Af[(long)lrow * K + gk0 + 4];
            float vv[8] = {v0.x, v0.y, v0.z, v0.w, v1.x, v1.y, v1.z, v1.w};
            int grow = blockIdx.y * 64 + lrow;
            float sc = rsqrtf((float)((grow & 127) + 1)) * (1.0f / 92681.900089f);
            #pragma unroll
            for (int j = 0; j < 8; ++j)
                As[lrow][lk + j] = __float2bfloat16(gelu_f(vv[j] * sc + ro_b1[gk0 + j]));
        }
        *(float4*)&Bs[lrow][lk] = *(const float4*)&Bb[(long)lrow * K + kt + lk];
        __syncthreads();
        short8t a0 = *(const short8t*)&As[wr + fm][fk];
        short8t a1 = *(const short8t*)&As[wr + 16 + fm][fk];
        short8t b0 = *(const short8t*)&Bs[wc + fm][fk];
        short8t b1 = *(const short8t*)&Bs[wc + 16 + fm][fk];
        acc00 = __builtin_amdgcn_mfma_f32_16x16x32_bf16(a0, b0, acc00, 0, 0, 0);
        acc01 = __builtin_amdgcn_mfma_f32_16x16x32_bf16(a0, b1, acc01, 0, 0, 0);
        acc10 = __builtin_amdgcn_mfma_f32_16x16x32_bf16(a1, b0, acc10, 0, 0, 0);
        acc11 = __builtin_amdgcn_mfma_f32_16x16x32_bf16(a1, b1, acc11, 0, 0, 0);
        __syncthreads();
    }

    const float* bias = mode ? ro_b2 : vp_b2;
    float* Cf = mode ? hfeat : vf;
    int row_base = blockIdx.y * 64 + wr + (lane >> 4) * 4;
    int col_base = blockIdx.x * 64 + wc + fm;
    #pragma unroll
    for (int fr = 0; fr < 2; ++fr) {
        #pragma unroll
        for (int fc = 0; fc < 2; ++fc) {
            const f32x4& a = fr == 0 ? (fc == 0 ? acc00 : acc01) : (fc == 0 ? acc10 : acc11);
            #pragma unroll
            for (int r = 0; r < 4; ++r) {
                int gi = row_base + fr * 16 + r;
                int gj = col_base + fc * 16;
                Cf[(long)gi * 512 + gj] = a[r] + bias[gj];
            }
        }
    }
}

// LN over D=512. FINAL=0: LN(x1); FINAL=1: LN(x1 + gf*x2 + gv*x3). OB16 selects out dtype.
template<int FINAL, int OB16>
__global__ __launch_bounds__(256) void ln_kernel(const float* __restrict__ x1,
                                                 const float* __restrict__ x2,
                                                 const float* __restrict__ x3,
                                                 const float* __restrict__ g,
                                                 const float* __restrict__ bb,
                                                 const float* __restrict__ scal,
                                                 void* __restrict__ outv) {
    int row = blockIdx.x, tid = threadIdx.x;
    long base = (long)row * D_;
    int d0 = tid, d1 = tid + 256;
    float v0, v1;
    if (FINAL) {
        float gf = scal[3], gv = scal[4];
        v0 = x1[base + d0] + gf * x2[base + d0] + gv * x3[base + d0];
        v1 = x1[base + d1] + gf * x2[base + d1] + gv * x3[base + d1];
    } else {
        v0 = x1[base + d0];
        v1 = x1[base + d1];
    }
    float s = v0 + v1;
    #pragma unroll
    for (int o = 32; o > 0; o >>= 1) s += __shfl_down(s, o);
    __shared__ float red[8];
    int wid = tid >> 6, lane = tid & 63;
    if (lane == 0) red[wid] = s;
    __syncthreads();
    float mu = (red[0] + red[1] + red[2] + red[3]) * (1.0f / D_);
    float e0 = v0 - mu, e1 = v1 - mu;
    float sq = e0 * e0 + e1 * e1;
    #pragma unroll
    for (int o = 32; o > 0; o >>= 1) sq += __shfl_down(sq, o);
    if (lane == 0) red[4 + wid] = sq;
    __syncthreads();
    float var = (red[4] + red[5] + red[6] + red[7]) * (1.0f / D_);
    float rs = rsqrtf(var + 1e-5f);
    float o0 = e0 * rs * g[d0] + bb[d0];
    float o1 = e1 * rs * g[d1] + bb[d1];
    if (OB16) {
        ((bf16*)outv)[base + d0] = __float2bfloat16(o0);
        ((bf16*)outv)[base + d1] = __float2bfloat16(o1);
    } else {
        ((float*)outv)[base + d0] = o0;
        ((float*)outv)[base + d1] = o1;
    }
}

extern "C" void kernel_launch(void* const* d_in, const int* in_sizes, int n_in,
                              void* d_out, int out_size, void* d_ws, size_t ws_size,
                              hipStream_t stream) {
    const float* e      = (const float*)d_in[0];
    const int*   h      = (const int*)d_in[1];
    const float* sign   = (const float*)d_in[2];
    const float* Wq     = (const float*)d_in[3];
    const float* Wk     = (const float*)d_in[4];
    const float* Wv     = (const float*)d_in[5];
    const float* ro_w1  = (const float*)d_in[6];
    const float* ro_b1  = (const float*)d_in[7];
    const float* ro_w2  = (const float*)d_in[8];
    const float* ro_b2  = (const float*)d_in[9];
    const float* vp_ln_g= (const float*)d_in[10];
    const float* vp_ln_b= (const float*)d_in[11];
    const float* vp_w1  = (const float*)d_in[12];
    const float* vp_b1  = (const float*)d_in[13];
    const float* vp_w2  = (const float*)d_in[14];
    const float* vp_b2  = (const float*)d_in[15];
    const float* ln_g   = (const float*)d_in[16];
    const float* ln_b   = (const float*)d_in[17];
    const float* tq     = (const float*)d_in[18];
    const float* tk     = (const float*)d_in[19];
    const float* om     = (const float*)d_in[20];
    const float* gfr    = (const float*)d_in[21];
    const float* gvr    = (const float*)d_in[22];

    float* ws    = (float*)d_ws;
    float* scal  = ws + OFF_SCAL;
    float* qkv   = ws + OFF_QKV;
    float* vraw  = ws + OFF_VRAW;
    float* vf    = ws + OFF_VF;
    float* hfeat = ws + OFF_HFEAT;
    float* scoacc= ws + OFF_SCOA;
    float* qsum  = ws + OFF_QSUM;
    float* hacc  = ws + OFF_HACC;
    bf16* kp16  = (bf16*)(ws + OFF_KP);
    bf16* eb    = (bf16*)(ws + OFF_EB);
    bf16* wqkvT = (bf16*)(ws + OFF_WQKVT);
    bf16* vp1T  = (bf16*)(ws + OFF_VP1T);
    bf16* vp2T  = (bf16*)(ws + OFF_VP2T);
    bf16* ro2T  = (bf16*)(ws + OFF_RO2T);
    bf16* qcat  = (bf16*)(ws + OFF_QCAT);
    bf16* kcat  = (bf16*)(ws + OFF_KCAT);
    bf16* dkT   = (bf16*)(ws + OFF_DKT);
    bf16* vTb   = (bf16*)(ws + OFF_VTB);
    bf16* vlnb  = (bf16*)(ws + OFF_VLNB);
    bf16* v1b   = (bf16*)(ws + OFF_V1B);
    bf16* pcat  = (bf16*)(ws + OFF_PCAT);
    bf16* ro1f  = (bf16*)(ws + OFF_RO1F);

    float* ys = (float*)d_out;
    float* kf = ys + (long)BT_ * D_;
    float* hf = kf + (long)B_ * 2 * M_;

    // fused preprocessing: scal+zero | e-cast | weight transposes | ro1 FFT
    preproc_kernel<<<3200, 256, 0, stream>>>(
        tq, tk, om, gfr, gvr, scal, scoacc, hacc,
        (const float4*)e, (ushort4t*)eb,
        Wq, Wk, Wv, vp_w1, vp_w2, ro_w2,
        wqkvT, wqkvT + 262144, wqkvT + 524288, vp1T, vp2T, ro2T,
        ro_w1, ro1f);

    // qkv = e @ [Wq|Wk|Wv]  (1024 x 1536 x 512) -> f32
    gemm_mfma<0, 0, 0><<<dim3(24, 16, 1), 256, 0, stream>>>(
        eb, wqkvT, nullptr, nullptr, qkv, 512, 1536, 0, 0, 0, 1);

    // fused sketch + vTb transpose
    sketchvtb_kernel<<<1536, 256, 0, stream>>>(qkv, sign, scal, h, qcat, kcat, vTb);

    // prefix over t reading bf16 kcat
    prefix_p1<<<512, 256, 0, stream>>>(kcat, qsum);
    prefix_p2<<<512, 256, 0, stream>>>(kcat, qsum, kp16, dkT, kf);

    // fused: forward FFTs + spectral product | scores split-K GEMM | Hf GEMM
    fftscohf_kernel<<<5504, 256, 0, stream>>>(qcat, kp16, pcat, kcat, scoacc, vTb, dkT, hf);

    // vraw[b] = masked(scores) @ v * rsqrt(t+1)  (mask fused in A-load)
    gemm_mfma<FLAG_ROWSCALE, 0, 1><<<dim3(8, 2, 8), 256, 0, stream>>>(
        scoacc, vTb, nullptr, nullptr, vraw, 128, 512, 16384, 65536, 65536, 1);

    ln_kernel<0, 1><<<1024, 256, 0, stream>>>(vraw, nullptr, nullptr, vp_ln_g, vp_ln_b, scal, vlnb);

    // fused: v1b = gelu(vlnb@vp1T+b1) | hid_pre split-K atomic into hacc
    v1hid_kernel<<<384, 256, 0, stream>>>(vlnb, vp1T, vp_b1, v1b, pcat, ro1f, hacc);

    // fused: vf = v1b@vp2T + b2  ||  hfeat = gelu(hacc*scale+ro_b1)@ro2T + ro_b2
    gemm_dual<<<dim3(8, 16, 2), 256, 0, stream>>>(
        v1b, vp2T, vp_b2, hacc, ro2T, ro_b1, ro_b2, vf, hfeat);

    // ys = LN(e + gf*hfeat + gv*vf)
    ln_kernel<1, 0><<<1024, 256, 0, stream>>>(e, hfeat, vf, ln_g, ln_b, scal, ys);
}

// Round 18
// 131.770 us; speedup vs baseline: 1.1603x; 1.1603x over previous
//
#include <hip/hip_runtime.h>
#include <hip/hip_bf16.h>
#include <math.h>

#define B_   8
#define T_   128
#define D_   512
#define M_   2048
#define HID_ 128
#define BT_  1024

typedef __attribute__((ext_vector_type(8))) short short8t;
typedef __attribute__((ext_vector_type(8))) unsigned short ushort8t;
typedef __attribute__((ext_vector_type(4))) unsigned short ushort4t;
typedef __attribute__((ext_vector_type(4))) float f32x4;
typedef __hip_bfloat16 bf16;

// ws layout (float offsets; all multiples of 16 -> 64B aligned)
#define OFF_SCAL   0L
#define OFF_QKV    16L                            // 1024*1536 f32
#define OFF_KP     (OFF_QKV + 1572864L)           // [KR|KI] bf16 exclusive prefix (2*BT*M bf16)
#define OFF_VRAW   (OFF_KP + 2097152L)
#define OFF_VF     (OFF_VRAW + 524288L)
#define OFF_HFEAT  (OFF_VF + 524288L)
// bf16 buffers (size in floats = elems/2)
#define OFF_EB     (OFF_HFEAT + 524288L)          // 1024x512
#define OFF_WQKVT  (OFF_EB + 262144L)             // 1536x512
#define OFF_VP1T   (OFF_WQKVT + 393216L)          // 512x512
#define OFF_VP2T   (OFF_VP1T + 131072L)
#define OFF_RO2T   (OFF_VP2T + 131072L)           // 512x128
#define OFF_QCAT   (OFF_RO2T + 32768L)            // 1024x4096
#define OFF_KCAT   (OFF_QCAT + 2097152L)          // 1024x4096
#define OFF_DKT    (OFF_KCAT + 2097152L)          // 2x8x2048x128
#define OFF_VTB    (OFF_DKT + 2097152L)           // 8x512x128
#define OFF_VLNB   (OFF_VTB + 262144L)            // 1024x512
#define OFF_V1B    (OFF_VLNB + 262144L)           // 1024x512
#define OFF_SCOA   (OFF_V1B + 262144L)            // 8x128x128 f32 split-K accumulator
#define OFF_QSUM   (OFF_SCOA + 131072L)           // 4x32768 f32 prefix quarter sums
#define OFF_PCAT   (OFF_QSUM + 131072L)           // 1024x4096 bf16 [ReP|ImP]
#define OFF_RO1F   (OFF_PCAT + 2097152L)          // 128x4096 bf16 [ReG|ImG]
#define OFF_HACC   (OFF_RO1F + 262144L)           // 1024x128 f32

#define FLAG_BIAS     1
#define FLAG_GELU     2
#define FLAG_ROWSCALE 4
#define FLAG_ATOMIC   8
#define FLAG_HFB      32

__device__ __forceinline__ float gelu_f(float x) {
    return 0.5f * x * (1.0f + erff(x * 0.70710678118654752440f));
}

__device__ __forceinline__ float b2f(unsigned short u) {
    return __uint_as_float(((unsigned int)u) << 16);
}

#define PIDX(i) ((i) + ((i) >> 5))

template<int M>
__device__ __forceinline__ void dif_one(float* re, float* im, int tid) {
    #pragma unroll
    for (int u = 0; u < 4; ++u) {
        int q = u * 256 + tid;
        int k = q & (M - 1);
        int i = (q / M) * (2 * M) + k;
        float s, c;
        __sincosf((float)k * (3.14159265358979323846f / (float)M), &s, &c);
        int p0 = PIDX(i), p1 = PIDX(i + M);
        float ar = re[p0], ai = im[p0], br = re[p1], bi = im[p1];
        re[p0] = ar + br; im[p0] = ai + bi;
        float dr = ar - br, di = ai - bi;
        re[p1] = dr * c + di * s;
        im[p1] = di * c - dr * s;
    }
}

// ==== fused preprocessing: scal+zero | e-cast | 6x weight transpose | ro1 FFT ====
__global__ __launch_bounds__(256) void preproc_kernel(
    const float* tq, const float* tk, const float* om, const float* gf, const float* gv,
    float* scal, float* scoacc, float* hacc,
    const float4* __restrict__ e4, ushort4t* __restrict__ eb4,
    const float* w0, const float* w1, const float* w2, const float* w3,
    const float* w4, const float* w5,
    bf16* d0, bf16* d1, bf16* d2, bf16* d3, bf16* d4, bf16* d5,
    const float* __restrict__ ro_w1, bf16* __restrict__ ro1f)
{
    __shared__ float smem[4224];   // 16.9 KB union
    int blk = blockIdx.x, tid = threadIdx.x;

    if (blk < 1024) {
        int idx = blk * 256 + tid;
        if (idx < 131072) scoacc[idx] = 0.f;
        else hacc[idx - 131072] = 0.f;
        if (idx == 0) {
            scal[0] = 0.5f * tanhf(tq[0]);
            scal[1] = 0.5f * tanhf(tk[0]);
            scal[2] = 0.5f * tanhf(om[0]);
            scal[3] = 0.25f / (1.0f + expf(-gf[0]));
            scal[4] = 0.25f / (1.0f + expf(-gv[0]));
        }
        return;
    }
    if (blk < 1536) {
        int i = (blk - 1024) * 256 + tid;   // < 131072
        float4 v = e4[i];
        ushort4t o;
        bf16 h0 = __float2bfloat16(v.x), h1 = __float2bfloat16(v.y);
        bf16 h2 = __float2bfloat16(v.z), h3 = __float2bfloat16(v.w);
        o[0] = *(unsigned short*)&h0; o[1] = *(unsigned short*)&h1;
        o[2] = *(unsigned short*)&h2; o[3] = *(unsigned short*)&h3;
        eb4[i] = o;
        return;
    }
    if (blk < 3072) {
        int zz = blk - 1536;
        int wz = zz >> 8;
        int rem = zz & 255;
        int by = rem >> 4, bx = rem & 15;
        const float* src; bf16* dst; int R = 512;
        if (wz == 0)      { src = w0; dst = d0; }
        else if (wz == 1) { src = w1; dst = d1; }
        else if (wz == 2) { src = w2; dst = d2; }
        else if (wz == 3) { src = w3; dst = d3; }
        else if (wz == 4) { src = w4; dst = d4; }
        else              { src = w5; dst = d5; R = 128; }
        int c0 = bx * 32, r0 = by * 32;
        if (r0 >= R) return;
        float (*tile)[33] = (float(*)[33])smem;
        int tx = tid & 31, ty = tid >> 5;
        for (int rr = ty; rr < 32; rr += 8) {
            int r = r0 + rr;
            tile[rr][tx] = (r < R) ? src[(long)r * 512 + c0 + tx] : 0.f;
        }
        __syncthreads();
        int r = r0 + tx;
        if (r < R)
            for (int cc = ty; cc < 32; cc += 8)
                dst[(long)(c0 + cc) * R + r] = __float2bfloat16(tile[tx][cc]);
        return;
    }
    {   // ro1fft
        int j = blk - 3072;
        float* Rs = smem;
        float* Is = smem + 2112;
        for (int u = 0; u < 8; ++u) {
            int n = u * 256 + tid;
            Rs[PIDX(n)] = ro_w1[(long)n * HID_ + j];
            Is[PIDX(n)] = 0.f;
        }
        __syncthreads();
#define FSTEP(MM) dif_one<MM>(Rs, Is, tid); __syncthreads();
        FSTEP(1024) FSTEP(512) FSTEP(256) FSTEP(128) FSTEP(64)
        FSTEP(32) FSTEP(16) FSTEP(8) FSTEP(4) FSTEP(2) FSTEP(1)
#undef FSTEP
        unsigned short* op = (unsigned short*)(ro1f + (long)j * 4096);
        for (int u = 0; u < 8; ++u) {
            int r = u * 256 + tid;
            int pr = PIDX(r);
            bf16 re = __float2bfloat16(Rs[pr]);
            bf16 im = __float2bfloat16(Is[pr]);
            op[r]        = *(unsigned short*)&re;
            op[2048 + r] = *(unsigned short*)&im;
        }
    }
}

// ==== fused sketch + vTb transpose ====
__global__ __launch_bounds__(256) void sketchvtb_kernel(const float* __restrict__ qkv,
                                                        const float* __restrict__ sign,
                                                        const float* __restrict__ scal,
                                                        const int* __restrict__ h,
                                                        bf16* __restrict__ qcat,
                                                        bf16* __restrict__ kcat,
                                                        bf16* __restrict__ vTb) {
    __shared__ float smem[4 * M_];
    int blk = blockIdx.x, tid = threadIdx.x;
    if (blk < 1024) {
        int bt = blk;
        float* s0 = smem;
        float* s1 = smem + M_;
        float* s2 = smem + 2 * M_;
        float* s3 = smem + 3 * M_;
        for (int j = tid; j < M_; j += 256) { s0[j] = 0.f; s1[j] = 0.f; s2[j] = 0.f; s3[j] = 0.f; }
        __syncthreads();
        int t = bt & 127;
        float thq = scal[0], thk = scal[1], omg = scal[2];
        float ft = (float)t;
        for (int i = tid; i < D_; i += 256) {
            float q = qkv[(long)bt * 1536 + i];
            float k = qkv[(long)bt * 1536 + 512 + i];
            float sg = sign[i];
            float sq_, cq_, sk_, ck_;
            __sincosf(thq * q - omg * ft, &sq_, &cq_);
            __sincosf(thk * k + omg * ft, &sk_, &ck_);
            int m = h[i];
            atomicAdd(&s0[m], q * cq_ * sg);
            atomicAdd(&s1[m], q * sq_ * sg);
            atomicAdd(&s2[m], k * ck_ * sg);
            atomicAdd(&s3[m], k * sk_ * sg);
        }
        __syncthreads();
        long qb = (long)bt * 4096;
        for (int j = tid; j < M_; j += 256) {
            qcat[qb + j]        = __float2bfloat16(s0[j]);
            qcat[qb + 2048 + j] = __float2bfloat16(s1[j]);
            kcat[qb + j]        = __float2bfloat16(s2[j]);
            kcat[qb + 2048 + j] = __float2bfloat16(-s3[j]);
        }
        return;
    }
    {   // vTb transpose
        int zz = blk - 1024;
        int b = zz >> 6;
        int rem = zz & 63;
        int by = rem >> 4, bx = rem & 15;
        int c0 = bx * 32, r0 = by * 32;
        float (*tile)[33] = (float(*)[33])smem;
        int tx = tid & 31, ty = tid >> 5;
        const float* in = qkv + 1024 + (long)b * 196608L;
        for (int rr = ty; rr < 32; rr += 8)
            tile[rr][tx] = in[(long)(r0 + rr) * 1536 + c0 + tx];
        __syncthreads();
        bf16* out = vTb + (long)b * 65536L;
        for (int cc = ty; cc < 32; cc += 8)
            out[(long)(c0 + cc) * 128 + r0 + tx] = __float2bfloat16(tile[tx][cc]);
    }
}

// ---- two-phase exclusive prefix over t, reading bf16 kcat ----
__global__ __launch_bounds__(256) void prefix_p1(const bf16* __restrict__ kcat,
                                                 float* __restrict__ qsum) {
    int idx = blockIdx.x * 256 + threadIdx.x;   // 131072
    int col = idx & 32767, q = idx >> 15;
    int m = col & 2047, b = (col >> 11) & 7, comp = col >> 14;
    const unsigned short* src = (const unsigned short*)kcat
        + ((long)(b * 128 + q * 32) * 4096L + (long)comp * 2048L + m);
    float s = 0.f;
    #pragma unroll 8
    for (int i = 0; i < 32; ++i) s += b2f(src[(long)i * 4096L]);
    if (comp) s = -s;
    qsum[(long)q * 32768 + col] = s;
}

__global__ __launch_bounds__(256) void prefix_p2(const bf16* __restrict__ kcat,
                                                 const float* __restrict__ qsum,
                                                 bf16* __restrict__ KP16,
                                                 bf16* __restrict__ dkT,
                                                 float* __restrict__ kf_out) {
    int idx = blockIdx.x * 256 + threadIdx.x;   // 131072
    int col = idx & 32767, q = idx >> 15;
    int m = col & 2047, b = (col >> 11) & 7, comp = col >> 14;
    const unsigned short* src = (const unsigned short*)kcat
        + ((long)(b * 128 + q * 32) * 4096L + (long)comp * 2048L + m);
    bf16* dst = KP16 + (long)comp * BT_ * M_ + (long)b * T_ * M_ + m + (long)(q * 32) * M_;
    bf16* dkt = dkT + (long)comp * 2097152L + (long)b * 262144L + (long)m * 128L + (long)(q * 32);
    float acc = 0.f;
    for (int p = 0; p < q; ++p) acc += qsum[(long)p * 32768 + col];
    float sgn = comp ? -1.f : 1.f;
    #pragma unroll 4
    for (int i = 0; i < 32; ++i) {
        float v = sgn * b2f(src[(long)i * 4096L]);
        dst[(long)i * M_] = __float2bfloat16(acc);
        dkt[i] = __float2bfloat16(v);
        acc += v;
    }
    if (q == 3) kf_out[((long)b * 2 + comp) * M_ + m] = acc;
}

// fused 3-stage radix-8 DIF pass on both (K,Q) arrays.
template<int S>
__device__ __forceinline__ void dif8_pair(float* r0, float* i0a, float* r1, float* i1a, int tid) {
    int k = tid % S;
    int grp = tid / S;
    int base = grp * 8 * S + k;
    float sw, cw;
    __sincosf((float)k * (3.14159265358979323846f / (4.0f * (float)S)), &sw, &cw);
    float wr = cw, wi = -sw;
    float w2r = wr * wr - wi * wi, w2i = 2.f * wr * wi;
    float w4r = w2r * w2r - w2i * w2i, w4i = 2.f * w2r * w2i;
    const float RH = 0.70710678118654752440f;
    float t1r[4] = {wr, (wr + wi) * RH, wi, (wi - wr) * RH};
    float t1i[4] = {wi, (wi - wr) * RH, -wr, -(wr + wi) * RH};
    float u0r = w2r, u0i = w2i;
    float u1r = w2i, u1i = -w2r;
    #pragma unroll
    for (int a = 0; a < 2; ++a) {
        float* re = a ? r1 : r0;
        float* im = a ? i1a : i0a;
        float xr[8], xi[8];
        #pragma unroll
        for (int r = 0; r < 8; ++r) { int p = PIDX(base + r * S); xr[r] = re[p]; xi[r] = im[p]; }
        #pragma unroll
        for (int r = 0; r < 4; ++r) {
            float ar = xr[r], ai = xi[r], br = xr[r + 4], bi = xi[r + 4];
            xr[r] = ar + br; xi[r] = ai + bi;
            float dr = ar - br, di = ai - bi;
            xr[r + 4] = dr * t1r[r] - di * t1i[r];
            xi[r + 4] = dr * t1i[r] + di * t1r[r];
        }
        #pragma unroll
        for (int hb = 0; hb < 8; hb += 4) {
            #pragma unroll
            for (int r = 0; r < 2; ++r) {
                float tr = (r == 0) ? u0r : u1r, ti = (r == 0) ? u0i : u1i;
                float ar = xr[hb + r], ai = xi[hb + r], br = xr[hb + r + 2], bi = xi[hb + r + 2];
                xr[hb + r] = ar + br; xi[hb + r] = ai + bi;
                float dr = ar - br, di = ai - bi;
                xr[hb + r + 2] = dr * tr - di * ti;
                xi[hb + r + 2] = dr * ti + di * tr;
            }
        }
        #pragma unroll
        for (int r = 0; r < 8; r += 2) {
            float ar = xr[r], ai = xi[r], br = xr[r + 1], bi = xi[r + 1];
            xr[r] = ar + br; xi[r] = ai + bi;
            float dr = ar - br, di = ai - bi;
            xr[r + 1] = dr * w4r - di * w4i;
            xi[r + 1] = dr * w4i + di * w4r;
        }
        #pragma unroll
        for (int r = 0; r < 8; ++r) { int p = PIDX(base + r * S); re[p] = xr[r]; im[p] = xi[r]; }
    }
}

// GEMM inner body macro shared by fused launch kernels (bf16 TN, 64x64 tile)
#define GEMM_CORE(ABASE, BBASE, KK)                                            \
    for (int kt = k0; kt < k0 + klen; kt += 32) {                              \
        *(float4*)&As[lrow][lk] = *(const float4*)&(ABASE)[(long)lrow * (KK) + kt + lk]; \
        *(float4*)&Bs[lrow][lk] = *(const float4*)&(BBASE)[(long)lrow * (KK) + kt + lk]; \
        __syncthreads();                                                       \
        short8t a0 = *(const short8t*)&As[wr + fm][fk];                        \
        short8t a1 = *(const short8t*)&As[wr + 16 + fm][fk];                   \
        short8t b0 = *(const short8t*)&Bs[wc + fm][fk];                        \
        short8t b1 = *(const short8t*)&Bs[wc + 16 + fm][fk];                   \
        acc00 = __builtin_amdgcn_mfma_f32_16x16x32_bf16(a0, b0, acc00, 0, 0, 0); \
        acc01 = __builtin_amdgcn_mfma_f32_16x16x32_bf16(a0, b1, acc01, 0, 0, 0); \
        acc10 = __builtin_amdgcn_mfma_f32_16x16x32_bf16(a1, b0, acc10, 0, 0, 0); \
        acc11 = __builtin_amdgcn_mfma_f32_16x16x32_bf16(a1, b1, acc11, 0, 0, 0); \
        __syncthreads();                                                       \
    }

// ==== fused: fwdfft (blocks [0,1024)) | scores GEMM (blocks [1024,1408)) ====
__global__ __launch_bounds__(256) void fftsco_kernel(const bf16* __restrict__ qcat,
                                                     const bf16* __restrict__ KP16,
                                                     bf16* __restrict__ pcat,
                                                     const bf16* __restrict__ kcat,
                                                     float* __restrict__ scoacc) {
    __shared__ float smem[8448];   // 33 KB union (FFT: 4x2112 f32; GEMM: 2x1408 f32)
    int blk = blockIdx.x, tid = threadIdx.x;

    if (blk >= 1024) {   // ---- scores GEMM tile: flattened (3,1,128) TRI split-K ----
        int s = blk - 1024;            // [0,384)
        int xx = s % 3, bz = s / 3;    // bz in [0,128)
        int tby = (xx > 0) ? 1 : 0, tbx = (xx == 2) ? 1 : 0;
        int batch = bz >> 4, kslice = bz & 15;
        const int K = 4096;
        int klen = 256, k0 = kslice * 256;
        bf16 (*As)[44] = (bf16(*)[44])smem;
        bf16 (*Bs)[44] = (bf16(*)[44])(smem + 1408);
        const bf16* Ab = qcat + (long)batch * 524288L + (long)tby * 64 * K;
        const bf16* Bb = kcat + (long)batch * 524288L + (long)tbx * 64 * K;
        int lrow = tid >> 2, lk = (tid & 3) * 8;
        int w = tid >> 6, lane = tid & 63;
        int wr = (w >> 1) * 32, wc = (w & 1) * 32;
        int fm = lane & 15, fk = (lane >> 4) * 8;
        f32x4 acc00 = {0.f,0.f,0.f,0.f}, acc01 = acc00, acc10 = acc00, acc11 = acc00;
        GEMM_CORE(Ab, Bb, K)
        float* Cf = scoacc + (long)batch * 16384L;
        int row_base = tby * 64 + wr + (lane >> 4) * 4;
        int col_base = tbx * 64 + wc + fm;
        #pragma unroll
        for (int fr = 0; fr < 2; ++fr)
            #pragma unroll
            for (int fc = 0; fc < 2; ++fc) {
                const f32x4& a = fr == 0 ? (fc == 0 ? acc00 : acc01) : (fc == 0 ? acc10 : acc11);
                #pragma unroll
                for (int r = 0; r < 4; ++r)
                    atomicAdd(&Cf[(long)(row_base + fr * 16 + r) * 128 + col_base + fc * 16], a[r]);
            }
        return;
    }

    // ---- fwdfft per (b,t) ----
    float* KRs = smem;
    float* KIs = smem + 2112;
    float* QRs = smem + 4224;
    float* QIs = smem + 6336;
    int bt = blk;
    const unsigned short* qp = (const unsigned short*)(qcat + (long)bt * 4096);
    const unsigned short* kpr = (const unsigned short*)(KP16 + (long)bt * M_);
    const unsigned short* kpi = (const unsigned short*)(KP16 + (long)BT_ * M_ + (long)bt * M_);
    for (int u = 0; u < 8; ++u) {
        int j = u * 256 + tid;
        int pj = PIDX(j);
        KRs[pj] = b2f(kpr[j]);
        KIs[pj] = b2f(kpi[j]);
        QRs[pj] = b2f(qp[j]);
        QIs[pj] = b2f(qp[2048 + j]);
    }
    __syncthreads();
    dif8_pair<256>(KRs, KIs, QRs, QIs, tid);  __syncthreads();
    dif8_pair<32>(KRs, KIs, QRs, QIs, tid);   __syncthreads();

    float kr_[8], ki_[8], qr_[8], qi_[8];
    #pragma unroll
    for (int l = 0; l < 8; ++l) {
        int pj = PIDX(8 * tid + l);
        kr_[l] = KRs[pj]; ki_[l] = KIs[pj];
        qr_[l] = QRs[pj]; qi_[l] = QIs[pj];
    }

    const float C16[16] = {1.f, 0.98078528f, 0.92387953f, 0.83146961f,
                           0.70710678f, 0.55557023f, 0.38268343f, 0.19509032f,
                           0.f, -0.19509032f, -0.38268343f, -0.55557023f,
                           -0.70710678f, -0.83146961f, -0.92387953f, -0.98078528f};
    const float S16[16] = {0.f, 0.19509032f, 0.38268343f, 0.55557023f,
                           0.70710678f, 0.83146961f, 0.92387953f, 0.98078528f,
                           1.f, 0.98078528f, 0.92387953f, 0.83146961f,
                           0.70710678f, 0.55557023f, 0.38268343f, 0.19509032f};
    bool odd = (tid & 1) != 0;
    {
        bool hi2 = (tid & 2) != 0;
        #pragma unroll
        for (int l = 0; l < 8; ++l) {
            float c = odd ? C16[l + 8] : C16[l];
            float s = odd ? S16[l + 8] : S16[l];
            float pr, pi2, sr, si, dr, di;
            pr = __shfl_xor(kr_[l], 2); pi2 = __shfl_xor(ki_[l], 2);
            sr = kr_[l] + pr; si = ki_[l] + pi2;
            dr = pr - kr_[l]; di = pi2 - ki_[l];
            kr_[l] = hi2 ? (dr * c + di * s) : sr;
            ki_[l] = hi2 ? (di * c - dr * s) : si;
            pr = __shfl_xor(qr_[l], 2); pi2 = __shfl_xor(qi_[l], 2);
            sr = qr_[l] + pr; si = qi_[l] + pi2;
            dr = pr - qr_[l]; di = pi2 - qi_[l];
            qr_[l] = hi2 ? (dr * c + di * s) : sr;
            qi_[l] = hi2 ? (di * c - dr * s) : si;
        }
    }
    {
        #pragma unroll
        for (int l = 0; l < 8; ++l) {
            float c = C16[2 * l];
            float s = S16[2 * l];
            float pr, pi2, sr, si, dr, di;
            pr = __shfl_xor(kr_[l], 1); pi2 = __shfl_xor(ki_[l], 1);
            sr = kr_[l] + pr; si = ki_[l] + pi2;
            dr = pr - kr_[l]; di = pi2 - ki_[l];
            kr_[l] = odd ? (dr * c + di * s) : sr;
            ki_[l] = odd ? (di * c - dr * s) : si;
            pr = __shfl_xor(qr_[l], 1); pi2 = __shfl_xor(qi_[l], 1);
            sr = qr_[l] + pr; si = qi_[l] + pi2;
            dr = pr - qr_[l]; di = pi2 - qi_[l];
            qr_[l] = odd ? (dr * c + di * s) : sr;
            qi_[l] = odd ? (di * c - dr * s) : si;
        }
    }
    {
        const float C4[4] = {1.f, 0.70710678f, 0.f, -0.70710678f};
        const float S4[4] = {0.f, 0.70710678f, 1.f, 0.70710678f};
        #pragma unroll
        for (int l = 0; l < 4; ++l) {
            float ar, ai, br, bi, dr, di;
            ar = kr_[l]; ai = ki_[l]; br = kr_[l + 4]; bi = ki_[l + 4];
            kr_[l] = ar + br; ki_[l] = ai + bi;
            dr = ar - br; di = ai - bi;
            kr_[l + 4] = dr * C4[l] + di * S4[l];
            ki_[l + 4] = di * C4[l] - dr * S4[l];
            ar = qr_[l]; ai = qi_[l]; br = qr_[l + 4]; bi = qi_[l + 4];
            qr_[l] = ar + br; qi_[l] = ai + bi;
            dr = ar - br; di = ai - bi;
            qr_[l + 4] = dr * C4[l] + di * S4[l];
            qi_[l + 4] = di * C4[l] - dr * S4[l];
        }
    }
    #pragma unroll
    for (int b2 = 0; b2 < 8; b2 += 4) {
        {
            float ar = kr_[b2], ai = ki_[b2], br = kr_[b2 + 2], bi = ki_[b2 + 2];
            kr_[b2] = ar + br; ki_[b2] = ai + bi;
            kr_[b2 + 2] = ar - br; ki_[b2 + 2] = ai - bi;
            ar = qr_[b2]; ai = qi_[b2]; br = qr_[b2 + 2]; bi = qi_[b2 + 2];
            qr_[b2] = ar + br; qi_[b2] = ai + bi;
            qr_[b2 + 2] = ar - br; qi_[b2 + 2] = ai - bi;
        }
        {
            float ar = kr_[b2 + 1], ai = ki_[b2 + 1], br = kr_[b2 + 3], bi = ki_[b2 + 3];
            kr_[b2 + 1] = ar + br; ki_[b2 + 1] = ai + bi;
            float dr = ar - br, di = ai - bi;
            kr_[b2 + 3] = di; ki_[b2 + 3] = -dr;
            ar = qr_[b2 + 1]; ai = qi_[b2 + 1]; br = qr_[b2 + 3]; bi = qi_[b2 + 3];
            qr_[b2 + 1] = ar + br; qi_[b2 + 1] = ai + bi;
            dr = ar - br; di = ai - bi;
            qr_[b2 + 3] = di; qi_[b2 + 3] = -dr;
        }
    }
    #pragma unroll
    for (int i0 = 0; i0 < 8; i0 += 2) {
        float ar = kr_[i0], ai = ki_[i0], br = kr_[i0 + 1], bi = ki_[i0 + 1];
        kr_[i0] = ar + br; ki_[i0] = ai + bi;
        kr_[i0 + 1] = ar - br; ki_[i0 + 1] = ai - bi;
        ar = qr_[i0]; ai = qi_[i0]; br = qr_[i0 + 1]; bi = qi_[i0 + 1];
        qr_[i0] = ar + br; qi_[i0] = ai + bi;
        qr_[i0 + 1] = ar - br; qi_[i0 + 1] = ai - bi;
    }

    unsigned short* op = (unsigned short*)(pcat + (long)bt * 4096 + 8 * tid);
    ushort8t ore, oim;
    #pragma unroll
    for (int l = 0; l < 8; ++l) {
        float pr = qr_[l] * kr_[l] - qi_[l] * ki_[l];
        float pi2 = qr_[l] * ki_[l] + qi_[l] * kr_[l];
        bf16 hr = __float2bfloat16(pr);
        bf16 hi = __float2bfloat16(pi2);
        ore[l] = *(unsigned short*)&hr;
        oim[l] = *(unsigned short*)&hi;
    }
    *(ushort8t*)op = ore;
    *(ushort8t*)(op + 2048) = oim;
}

// ==== fused: v1b GEMM (blocks [0,128)) | hid split-K GEMM (blocks [128,384)) ====
__global__ __launch_bounds__(256) void v1hid_kernel(const bf16* __restrict__ vlnb,
                                                    const bf16* __restrict__ vp1T,
                                                    const float* __restrict__ vp_b1,
                                                    bf16* __restrict__ v1b,
                                                    const bf16* __restrict__ pcat,
                                                    const bf16* __restrict__ ro1f,
                                                    float* __restrict__ hacc) {
    __shared__ __align__(16) bf16 As[64][44];
    __shared__ __align__(16) bf16 Bs[64][44];
    int blk = blockIdx.x, tid = threadIdx.x;
    int lrow = tid >> 2, lk = (tid & 3) * 8;
    int w = tid >> 6, lane = tid & 63;
    int wr = (w >> 1) * 32, wc = (w & 1) * 32;
    int fm = lane & 15, fk = (lane >> 4) * 8;
    f32x4 acc00 = {0.f,0.f,0.f,0.f}, acc01 = acc00, acc10 = acc00, acc11 = acc00;

    if (blk < 128) {   // v1b = gelu(vlnb @ vp1T^T + vp_b1), K=512
        int tbx = blk & 7, tby = blk >> 3;
        const int K = 512;
        int klen = K, k0 = 0;
        const bf16* Ab = vlnb + (long)tby * 64 * K;
        const bf16* Bb = vp1T + (long)tbx * 64 * K;
        GEMM_CORE(Ab, Bb, K)
        int row_base = tby * 64 + wr + (lane >> 4) * 4;
        int col_base = tbx * 64 + wc + fm;
        #pragma unroll
        for (int fr = 0; fr < 2; ++fr)
            #pragma unroll
            for (int fc = 0; fc < 2; ++fc) {
                const f32x4& a = fr == 0 ? (fc == 0 ? acc00 : acc01) : (fc == 0 ? acc10 : acc11);
                #pragma unroll
                for (int r = 0; r < 4; ++r) {
                    int gi = row_base + fr * 16 + r, gj = col_base + fc * 16;
                    v1b[(long)gi * 512 + gj] = __float2bfloat16(gelu_f(a[r] + vp_b1[gj]));
                }
            }
        return;
    }
    {   // hid_pre split-K: pcat(1024x4096) @ ro1f^T(128x4096), atomic into hacc
        int s2 = blk - 128;            // [0,256): (2,16,8) flatten
        int tbx = s2 & 1, tby = (s2 >> 1) & 15, kslice = s2 >> 5;
        const int K = 4096;
        int klen = 512, k0 = kslice * 512;
        const bf16* Ab = pcat + (long)tby * 64 * K;
        const bf16* Bb = ro1f + (long)tbx * 64 * K;
        GEMM_CORE(Ab, Bb, K)
        int row_base = tby * 64 + wr + (lane >> 4) * 4;
        int col_base = tbx * 64 + wc + fm;
        #pragma unroll
        for (int fr = 0; fr < 2; ++fr)
            #pragma unroll
            for (int fc = 0; fc < 2; ++fc) {
                const f32x4& a = fr == 0 ? (fc == 0 ? acc00 : acc01) : (fc == 0 ? acc10 : acc11);
                #pragma unroll
                for (int r = 0; r < 4; ++r)
                    atomicAdd(&hacc[(long)(row_base + fr * 16 + r) * 128 + col_base + fc * 16], a[r]);
            }
    }
}

// MFMA bf16 TN GEMM (generic; used for qkv, vraw, hf)
template<int FLAGS, int OUTB16, int AMODE>
__global__ __launch_bounds__(256) void gemm_mfma(
    const void* __restrict__ Av, const bf16* __restrict__ Bt,
    const float* __restrict__ bias, const float* __restrict__ abias,
    void* __restrict__ Cv,
    int K, int ldc, long abz, long bbz, long cbz, int splitk)
{
    __shared__ __align__(16) bf16 As[64][44];
    __shared__ __align__(16) bf16 Bs[64][44];
    int bz = blockIdx.z;
    int batch = bz, kslice = 0;
    if (FLAGS & FLAG_ATOMIC) { batch = bz / splitk; kslice = bz % splitk; }
    int tbx = blockIdx.x, tby = blockIdx.y;
    long aoff;
    const bf16* Bb;
    long coff;
    if (FLAGS & FLAG_HFB) {
        int b = bz & 7, c = bz >> 3;
        aoff = (long)b * abz + (long)tby * 64 * K;
        Bb = Bt + (long)c * 2097152L + (long)b * 262144L + (long)tbx * 64 * K;
        coff = (long)b * 2097152L + (long)c * 1048576L;
    } else {
        aoff = (long)batch * abz + (long)tby * 64 * K;
        Bb = Bt + (long)batch * bbz + (long)tbx * 64 * K;
        coff = (long)batch * cbz;
    }
    int tid = threadIdx.x;
    int lrow = tid >> 2;
    int lk = (tid & 3) * 8;
    int w = tid >> 6, lane = tid & 63;
    int wr = (w >> 1) * 32, wc = (w & 1) * 32;
    int fm = lane & 15, fk = (lane >> 4) * 8;
    f32x4 acc00 = {0.f,0.f,0.f,0.f}, acc01 = acc00, acc10 = acc00, acc11 = acc00;

    int klen = K / splitk;
    int k0 = kslice * klen;
    for (int kt = k0; kt < k0 + klen; kt += 32) {
        if (AMODE == 0) {
            const bf16* Ab = (const bf16*)Av + aoff;
            *(float4*)&As[lrow][lk] = *(const float4*)&Ab[(long)lrow * K + kt + lk];
        } else {
            const float* Af = (const float*)Av + aoff;
            int gk0 = kt + lk;
            float4 v0 = *(const float4*)&Af[(long)lrow * K + gk0];
            float4 v1 = *(const float4*)&Af[(long)lrow * K + gk0 + 4];
            float vv[8] = {v0.x, v0.y, v0.z, v0.w, v1.x, v1.y, v1.z, v1.w};
            int grow = tby * 64 + lrow;
            #pragma unroll
            for (int j = 0; j < 8; ++j) {
                float val = vv[j];
                int gk = gk0 + j;
                if (AMODE == 1) val = (gk < grow) ? val : 0.f;
                As[lrow][lk + j] = __float2bfloat16(val);
            }
        }
        *(float4*)&Bs[lrow][lk] = *(const float4*)&Bb[(long)lrow * K + kt + lk];
        __syncthreads();
        short8t a0 = *(const short8t*)&As[wr + fm][fk];
        short8t a1 = *(const short8t*)&As[wr + 16 + fm][fk];
        short8t b0 = *(const short8t*)&Bs[wc + fm][fk];
        short8t b1 = *(const short8t*)&Bs[wc + 16 + fm][fk];
        acc00 = __builtin_amdgcn_mfma_f32_16x16x32_bf16(a0, b0, acc00, 0, 0, 0);
        acc01 = __builtin_amdgcn_mfma_f32_16x16x32_bf16(a0, b1, acc01, 0, 0, 0);
        acc10 = __builtin_amdgcn_mfma_f32_16x16x32_bf16(a1, b0, acc10, 0, 0, 0);
        acc11 = __builtin_amdgcn_mfma_f32_16x16x32_bf16(a1, b1, acc11, 0, 0, 0);
        __syncthreads();
    }

    float* Cf = (float*)Cv;
    bf16* Cb = (bf16*)Cv;
    int row_base = tby * 64 + wr + (lane >> 4) * 4;
    int col_base = tbx * 64 + wc + fm;
    #pragma unroll
    for (int fr = 0; fr < 2; ++fr) {
        #pragma unroll
        for (int fc = 0; fc < 2; ++fc) {
            const f32x4& a = fr == 0 ? (fc == 0 ? acc00 : acc01) : (fc == 0 ? acc10 : acc11);
            #pragma unroll
            for (int r = 0; r < 4; ++r) {
                int gi = row_base + fr * 16 + r;
                int gj = col_base + fc * 16;
                float v = a[r];
                long ci = coff + (long)gi * ldc + gj;
                if (FLAGS & FLAG_ATOMIC) {
                    atomicAdd(&Cf[ci], v);
                } else {
                    if (FLAGS & FLAG_BIAS) v += bias[gj];
                    if (FLAGS & FLAG_GELU) v = gelu_f(v);
                    if (FLAGS & FLAG_ROWSCALE) v *= rsqrtf((float)(gi & 127) + 1.0f);
                    if (OUTB16) Cb[ci] = __float2bfloat16(v);
                    else        Cf[ci] = v;
                }
            }
        }
    }
}

// fused dual GEMM: z=0: vf = v1b @ vp2T^T + vp_b2;  z=1: hfeat = gelu(hacc..) @ ro2T^T + ro_b2
__global__ __launch_bounds__(256) void gemm_dual(
    const bf16* __restrict__ v1b, const bf16* __restrict__ vp2T, const float* __restrict__ vp_b2,
    const float* __restrict__ hacc, const bf16* __restrict__ ro2T, const float* __restrict__ ro_b1,
    const float* __restrict__ ro_b2, float* __restrict__ vf, float* __restrict__ hfeat)
{
    __shared__ __align__(16) bf16 As[64][44];
    __shared__ __align__(16) bf16 Bs[64][44];
    int tid = threadIdx.x;
    int lrow = tid >> 2, lk = (tid & 3) * 8;
    int w = tid >> 6, lane = tid & 63;
    int wr = (w >> 1) * 32, wc = (w & 1) * 32;
    int fm = lane & 15, fk = (lane >> 4) * 8;
    f32x4 acc00 = {0.f,0.f,0.f,0.f}, acc01 = acc00, acc10 = acc00, acc11 = acc00;
    int mode = blockIdx.z;
    int K = mode ? 128 : 512;
    const bf16* Bb = (mode ? ro2T : vp2T) + (long)blockIdx.x * 64 * K;

    for (int kt = 0; kt < K; kt += 32) {
        if (mode == 0) {
            const bf16* Ab = v1b + (long)blockIdx.y * 64 * K;
            *(float4*)&As[lrow][lk] = *(const float4*)&Ab[(long)lrow * K + kt + lk];
        } else {
            const float* Af = hacc + (long)blockIdx.y * 64 * K;
            int gk0 = kt + lk;
            float4 v0 = *(const float4*)&Af[(long)lrow * K + gk0];
            float4 v1 = *(const float4*)&Af[(long)lrow * K + gk0 + 4];
            float vv[8] = {v0.x, v0.y, v0.z, v0.w, v1.x, v1.y, v1.z, v1.w};
            int grow = blockIdx.y * 64 + lrow;
            float sc = rsqrtf((float)((grow & 127) + 1)) * (1.0f / 92681.900089f);
            #pragma unroll
            for (int j = 0; j < 8; ++j)
                As[lrow][lk + j] = __float2bfloat16(gelu_f(vv[j] * sc + ro_b1[gk0 + j]));
        }
        *(float4*)&Bs[lrow][lk] = *(const float4*)&Bb[(long)lrow * K + kt + lk];
        __syncthreads();
        short8t a0 = *(const short8t*)&As[wr + fm][fk];
        short8t a1 = *(const short8t*)&As[wr + 16 + fm][fk];
        short8t b0 = *(const short8t*)&Bs[wc + fm][fk];
        short8t b1 = *(const short8t*)&Bs[wc + 16 + fm][fk];
        acc00 = __builtin_amdgcn_mfma_f32_16x16x32_bf16(a0, b0, acc00, 0, 0, 0);
        acc01 = __builtin_amdgcn_mfma_f32_16x16x32_bf16(a0, b1, acc01, 0, 0, 0);
        acc10 = __builtin_amdgcn_mfma_f32_16x16x32_bf16(a1, b0, acc10, 0, 0, 0);
        acc11 = __builtin_amdgcn_mfma_f32_16x16x32_bf16(a1, b1, acc11, 0, 0, 0);
        __syncthreads();
    }

    const float* bias = mode ? ro_b2 : vp_b2;
    float* Cf = mode ? hfeat : vf;
    int row_base = blockIdx.y * 64 + wr + (lane >> 4) * 4;
    int col_base = blockIdx.x * 64 + wc + fm;
    #pragma unroll
    for (int fr = 0; fr < 2; ++fr) {
        #pragma unroll
        for (int fc = 0; fc < 2; ++fc) {
            const f32x4& a = fr == 0 ? (fc == 0 ? acc00 : acc01) : (fc == 0 ? acc10 : acc11);
            #pragma unroll
            for (int r = 0; r < 4; ++r) {
                int gi = row_base + fr * 16 + r;
                int gj = col_base + fc * 16;
                Cf[(long)gi * 512 + gj] = a[r] + bias[gj];
            }
        }
    }
}

// LN over D=512. FINAL=0: LN(x1); FINAL=1: LN(x1 + gf*x2 + gv*x3). OB16 selects out dtype.
template<int FINAL, int OB16>
__global__ __launch_bounds__(256) void ln_kernel(const float* __restrict__ x1,
                                                 const float* __restrict__ x2,
                                                 const float* __restrict__ x3,
                                                 const float* __restrict__ g,
                                                 const float* __restrict__ bb,
                                                 const float* __restrict__ scal,
                                                 void* __restrict__ outv) {
    int row = blockIdx.x, tid = threadIdx.x;
    long base = (long)row * D_;
    int d0 = tid, d1 = tid + 256;
    float v0, v1;
    if (FINAL) {
        float gf = scal[3], gv = scal[4];
        v0 = x1[base + d0] + gf * x2[base + d0] + gv * x3[base + d0];
        v1 = x1[base + d1] + gf * x2[base + d1] + gv * x3[base + d1];
    } else {
        v0 = x1[base + d0];
        v1 = x1[base + d1];
    }
    float s = v0 + v1;
    #pragma unroll
    for (int o = 32; o > 0; o >>= 1) s += __shfl_down(s, o);
    __shared__ float red[8];
    int wid = tid >> 6, lane = tid & 63;
    if (lane == 0) red[wid] = s;
    __syncthreads();
    float mu = (red[0] + red[1] + red[2] + red[3]) * (1.0f / D_);
    float e0 = v0 - mu, e1 = v1 - mu;
    float sq = e0 * e0 + e1 * e1;
    #pragma unroll
    for (int o = 32; o > 0; o >>= 1) sq += __shfl_down(sq, o);
    if (lane == 0) red[4 + wid] = sq;
    __syncthreads();
    float var = (red[4] + red[5] + red[6] + red[7]) * (1.0f / D_);
    float rs = rsqrtf(var + 1e-5f);
    float o0 = e0 * rs * g[d0] + bb[d0];
    float o1 = e1 * rs * g[d1] + bb[d1];
    if (OB16) {
        ((bf16*)outv)[base + d0] = __float2bfloat16(o0);
        ((bf16*)outv)[base + d1] = __float2bfloat16(o1);
    } else {
        ((float*)outv)[base + d0] = o0;
        ((float*)outv)[base + d1] = o1;
    }
}

extern "C" void kernel_launch(void* const* d_in, const int* in_sizes, int n_in,
                              void* d_out, int out_size, void* d_ws, size_t ws_size,
                              hipStream_t stream) {
    const float* e      = (const float*)d_in[0];
    const int*   h      = (const int*)d_in[1];
    const float* sign   = (const float*)d_in[2];
    const float* Wq     = (const float*)d_in[3];
    const float* Wk     = (const float*)d_in[4];
    const float* Wv     = (const float*)d_in[5];
    const float* ro_w1  = (const float*)d_in[6];
    const float* ro_b1  = (const float*)d_in[7];
    const float* ro_w2  = (const float*)d_in[8];
    const float* ro_b2  = (const float*)d_in[9];
    const float* vp_ln_g= (const float*)d_in[10];
    const float* vp_ln_b= (const float*)d_in[11];
    const float* vp_w1  = (const float*)d_in[12];
    const float* vp_b1  = (const float*)d_in[13];
    const float* vp_w2  = (const float*)d_in[14];
    const float* vp_b2  = (const float*)d_in[15];
    const float* ln_g   = (const float*)d_in[16];
    const float* ln_b   = (const float*)d_in[17];
    const float* tq     = (const float*)d_in[18];
    const float* tk     = (const float*)d_in[19];
    const float* om     = (const float*)d_in[20];
    const float* gfr    = (const float*)d_in[21];
    const float* gvr    = (const float*)d_in[22];

    float* ws    = (float*)d_ws;
    float* scal  = ws + OFF_SCAL;
    float* qkv   = ws + OFF_QKV;
    float* vraw  = ws + OFF_VRAW;
    float* vf    = ws + OFF_VF;
    float* hfeat = ws + OFF_HFEAT;
    float* scoacc= ws + OFF_SCOA;
    float* qsum  = ws + OFF_QSUM;
    float* hacc  = ws + OFF_HACC;
    bf16* kp16  = (bf16*)(ws + OFF_KP);
    bf16* eb    = (bf16*)(ws + OFF_EB);
    bf16* wqkvT = (bf16*)(ws + OFF_WQKVT);
    bf16* vp1T  = (bf16*)(ws + OFF_VP1T);
    bf16* vp2T  = (bf16*)(ws + OFF_VP2T);
    bf16* ro2T  = (bf16*)(ws + OFF_RO2T);
    bf16* qcat  = (bf16*)(ws + OFF_QCAT);
    bf16* kcat  = (bf16*)(ws + OFF_KCAT);
    bf16* dkT   = (bf16*)(ws + OFF_DKT);
    bf16* vTb   = (bf16*)(ws + OFF_VTB);
    bf16* vlnb  = (bf16*)(ws + OFF_VLNB);
    bf16* v1b   = (bf16*)(ws + OFF_V1B);
    bf16* pcat  = (bf16*)(ws + OFF_PCAT);
    bf16* ro1f  = (bf16*)(ws + OFF_RO1F);

    float* ys = (float*)d_out;
    float* kf = ys + (long)BT_ * D_;
    float* hf = kf + (long)B_ * 2 * M_;

    // fused preprocessing: scal+zero | e-cast | weight transposes | ro1 FFT
    preproc_kernel<<<3200, 256, 0, stream>>>(
        tq, tk, om, gfr, gvr, scal, scoacc, hacc,
        (const float4*)e, (ushort4t*)eb,
        Wq, Wk, Wv, vp_w1, vp_w2, ro_w2,
        wqkvT, wqkvT + 262144, wqkvT + 524288, vp1T, vp2T, ro2T,
        ro_w1, ro1f);

    // qkv = e @ [Wq|Wk|Wv]  (1024 x 1536 x 512) -> f32
    gemm_mfma<0, 0, 0><<<dim3(24, 16, 1), 256, 0, stream>>>(
        eb, wqkvT, nullptr, nullptr, qkv, 512, 1536, 0, 0, 0, 1);

    // fused sketch + vTb transpose
    sketchvtb_kernel<<<1536, 256, 0, stream>>>(qkv, sign, scal, h, qcat, kcat, vTb);

    // prefix over t reading bf16 kcat
    prefix_p1<<<512, 256, 0, stream>>>(kcat, qsum);
    prefix_p2<<<512, 256, 0, stream>>>(kcat, qsum, kp16, dkT, kf);

    // fused: forward FFTs + spectral product | scores split-K GEMM
    fftsco_kernel<<<1408, 256, 0, stream>>>(qcat, kp16, pcat, kcat, scoacc);

    // vraw[b] = masked(scores) @ v * rsqrt(t+1)  (mask fused in A-load)
    gemm_mfma<FLAG_ROWSCALE, 0, 1><<<dim3(8, 2, 8), 256, 0, stream>>>(
        scoacc, vTb, nullptr, nullptr, vraw, 128, 512, 16384, 65536, 65536, 1);

    ln_kernel<0, 1><<<1024, 256, 0, stream>>>(vraw, nullptr, nullptr, vp_ln_g, vp_ln_b, scal, vlnb);

    // fused: v1b = gelu(vlnb@vp1T+b1) | hid_pre split-K atomic into hacc
    v1hid_kernel<<<384, 256, 0, stream>>>(vlnb, vp1T, vp_b1, v1b, pcat, ro1f, hacc);

    // fused: vf = v1b@vp2T + b2  ||  hfeat = gelu(hacc*scale+ro_b1)@ro2T + ro_b2
    gemm_dual<<<dim3(8, 16, 2), 256, 0, stream>>>(
        v1b, vp2T, vp_b2, hacc, ro2T, ro_b1, ro_b2, vf, hfeat);

    // ys = LN(e + gf*hfeat + gv*vf)
    ln_kernel<1, 0><<<1024, 256, 0, stream>>>(e, hfeat, vf, ln_g, ln_b, scal, ys);

    // Hf fused: z in [0,16), b=z&7, c=z>>3  (own kernel: 11 KB LDS -> 8 blocks/CU)
    gemm_mfma<FLAG_HFB, 0, 0><<<dim3(32, 8, 16), 256, 0, stream>>>(
        vTb, dkT, nullptr, nullptr, hf, 128, 2048, 65536, 0, 0, 1);
}